// Round 1
// baseline (634.819 us; speedup 1.0000x reference)
//
#include <hip/hip_runtime.h>
#include <hip/hip_bf16.h>
#include <math.h>

// Problem: out[b,f,h,w] = sum_c M[f,c] * x[b,c,h,w]
// with M = Qinv @ diag(exp(-(T/tau)*|S|)) @ Q   (tau=0.5, alpha=1, T_param=1)
// B=4, C=64, H=W=512.

#define C_DIM 64
#define HW (512 * 512)

// ---- Kernel 1: precompute M[f,k] = sum_c Qinv[f,c] * d[c] * Q[c,k] ----
// d[c] = exp(-2 * T * |S[c]|)
// grid: 16 blocks x 256 threads -> 4096 entries, one per thread.
__global__ __launch_bounds__(256) void compute_M_kernel(
    const float* __restrict__ S, const float* __restrict__ Q,
    const float* __restrict__ Qinv, const int* __restrict__ Tp,
    float* __restrict__ M) {
    __shared__ float d[C_DIM];
    int tid = threadIdx.x;
    if (tid < C_DIM) {
        float t = (float)(*Tp);              // T_PARAM(=1) * T
        d[tid] = expf(-2.0f * t * fabsf(S[tid]));
    }
    __syncthreads();
    int gid = blockIdx.x * blockDim.x + tid;  // 0..4095
    int f = gid >> 6;
    int k = gid & 63;
    float acc = 0.0f;
    #pragma unroll
    for (int c = 0; c < C_DIM; ++c) {
        acc = fmaf(Qinv[f * C_DIM + c] * d[c], Q[c * C_DIM + k], acc);
    }
    M[gid] = acc;
}

// ---- Kernel 2: apply M to every pixel; 2 pixels (float2) per thread ----
// Consecutive lanes -> consecutive pixels -> coalesced dwordx2 per channel.
// M accesses are wave-uniform (loop-index only) -> scalar-cache s_loads.
__global__ __launch_bounds__(256) void apply_M_kernel(
    const float* __restrict__ x, const float* __restrict__ M,
    float* __restrict__ out) {
    const int str2 = HW / 2;  // channel stride in float2 units
    long long t = (long long)blockIdx.x * blockDim.x + threadIdx.x;  // 0..524287
    long long base = t * 2;                // pixel index in [0, B*HW)
    int b = (int)(base / HW);
    int s = (int)(base % HW);              // even, so both pixels share b

    const float2* xp = (const float2*)(x + ((size_t)b * C_DIM) * HW + s);
    float2* op = (float2*)(out + ((size_t)b * C_DIM) * HW + s);

    float2 xv[C_DIM];
    #pragma unroll
    for (int c = 0; c < C_DIM; ++c) {
        xv[c] = xp[(size_t)c * str2];
    }

    #pragma unroll 1
    for (int f = 0; f < C_DIM; ++f) {
        float ax = 0.0f, ay = 0.0f;
        #pragma unroll
        for (int c = 0; c < C_DIM; ++c) {
            float m = M[f * C_DIM + c];   // uniform -> SGPR via constant cache
            ax = fmaf(m, xv[c].x, ax);
            ay = fmaf(m, xv[c].y, ay);
        }
        op[(size_t)f * str2] = make_float2(ax, ay);
    }
}

extern "C" void kernel_launch(void* const* d_in, const int* in_sizes, int n_in,
                              void* d_out, int out_size, void* d_ws, size_t ws_size,
                              hipStream_t stream) {
    const float* x    = (const float*)d_in[0];
    const float* S    = (const float*)d_in[1];
    const float* Q    = (const float*)d_in[2];
    const float* Qinv = (const float*)d_in[3];
    const int*   Tp   = (const int*)d_in[4];
    float* out = (float*)d_out;
    float* M = (float*)d_ws;  // 64*64*4 = 16 KB scratch

    compute_M_kernel<<<16, 256, 0, stream>>>(S, Q, Qinv, Tp, M);

    // total pixels = 4 * 512*512 = 1,048,576; 2 pixels/thread -> 524,288 threads
    const int threads = 256;
    const int total_threads = (4 * HW) / 2;
    apply_M_kernel<<<total_threads / threads, threads, 0, stream>>>(x, M, out);
}

// Round 2
// 524.027 us; speedup vs baseline: 1.2114x; 1.2114x over previous
//
#include <hip/hip_runtime.h>
#include <hip/hip_bf16.h>
#include <math.h>

// out[b,f,h,w] = sum_c M[f,c] * x[b,c,h,w],  M = Qinv @ diag(exp(-2*T*|S|)) @ Q
// B=4, C=64, H=W=512.

#define C_DIM 64
#define HW (512 * 512)   // 2^18
#define CHUNK 16

// ---- Kernel 1: M[f,k] = sum_c Qinv[f,c] * d[c] * Q[c,k], d[c]=exp(-2T|S[c]|) ----
__global__ __launch_bounds__(256) void compute_M_kernel(
    const float* __restrict__ S, const float* __restrict__ Q,
    const float* __restrict__ Qinv, const int* __restrict__ Tp,
    float* __restrict__ M) {
    __shared__ float d[C_DIM];
    int tid = threadIdx.x;
    if (tid < C_DIM) {
        float t = (float)(*Tp);
        d[tid] = expf(-2.0f * t * fabsf(S[tid]));
    }
    __syncthreads();
    int gid = blockIdx.x * blockDim.x + tid;  // 0..4095
    int f = gid >> 6;
    int k = gid & 63;
    float acc = 0.0f;
    #pragma unroll
    for (int c = 0; c < C_DIM; ++c) {
        acc = fmaf(Qinv[f * C_DIM + c] * d[c], Q[c * C_DIM + k], acc);
    }
    M[gid] = acc;
}

// ---- Kernel 2: 1 pixel/thread, 64 fp32 accumulators, channel-chunked loads ----
// Chunk k+1's 16 loads are issued before chunk k's 1024 FMAs -> latency hidden.
// M accesses are thread-uniform -> scalar-cache s_loads (SGPR operand to v_fmac).
__global__ __launch_bounds__(256, 4) void apply_M_kernel(
    const float* __restrict__ x, const float* __restrict__ M,
    float* __restrict__ out) {
    int t = blockIdx.x * 256 + threadIdx.x;     // 0 .. 2^20-1
    int b = t >> 18;                            // pixel / HW
    int s = t & (HW - 1);                       // pixel % HW

    const float* xp = x + ((size_t)b * C_DIM) * HW + s;
    float*       op = out + ((size_t)b * C_DIM) * HW + s;

    float acc[C_DIM];
    #pragma unroll
    for (int f = 0; f < C_DIM; ++f) acc[f] = 0.0f;

    float xv[CHUNK], xn[CHUNK];
    #pragma unroll
    for (int c = 0; c < CHUNK; ++c) xv[c] = xp[(size_t)c * HW];

    #pragma unroll
    for (int chunk = 0; chunk < C_DIM / CHUNK; ++chunk) {
        // prefetch next chunk while this chunk's FMAs run
        if (chunk < C_DIM / CHUNK - 1) {
            #pragma unroll
            for (int c = 0; c < CHUNK; ++c)
                xn[c] = xp[(size_t)((chunk + 1) * CHUNK + c) * HW];
        }
        #pragma unroll
        for (int f = 0; f < C_DIM; ++f) {
            float a = acc[f];
            #pragma unroll
            for (int c = 0; c < CHUNK; ++c)
                a = fmaf(M[f * C_DIM + chunk * CHUNK + c], xv[c], a);
            acc[f] = a;
        }
        #pragma unroll
        for (int c = 0; c < CHUNK; ++c) xv[c] = xn[c];
    }

    #pragma unroll
    for (int f = 0; f < C_DIM; ++f) op[(size_t)f * HW] = acc[f];
}

extern "C" void kernel_launch(void* const* d_in, const int* in_sizes, int n_in,
                              void* d_out, int out_size, void* d_ws, size_t ws_size,
                              hipStream_t stream) {
    const float* x    = (const float*)d_in[0];
    const float* S    = (const float*)d_in[1];
    const float* Q    = (const float*)d_in[2];
    const float* Qinv = (const float*)d_in[3];
    const int*   Tp   = (const int*)d_in[4];
    float* out = (float*)d_out;
    float* M = (float*)d_ws;  // 16 KB scratch

    compute_M_kernel<<<16, 256, 0, stream>>>(S, Q, Qinv, Tp, M);

    // 4*HW pixels, 1 pixel per thread
    apply_M_kernel<<<(4 * HW) / 256, 256, 0, stream>>>(x, M, out);
}